// Round 5
// baseline (3568.626 us; speedup 1.0000x reference)
//
#include <hip/hip_runtime.h>
#include <hip/hip_bf16.h>

#define VOCAB 32000
#define HID 512
#define BATCH 256
#define SEQ 128
#define NL 5
#define BH (BATCH*HID)      // 131072
#define G4H (4*HID)         // 2048
#define NBLK_LAUNCH 256     // 32 blocks per XCD; 160 active (5 layers x 32)

// byte strides in h buffers: [slot][layer][j(32)][m(256)][c(16)] bf16
#define LAYB  (32*256*16*2)          // 262144 B per (slot,layer) slice
#define SLOTB (NL*LAYB)              // 1310720 B per slot

// flag layout (ints) in ws after export buffer
#define F_DONE(l)   ((l)*64)         // monotonic per-layer step counters
#define F_CLAIM(x)  (384 + (x)*8)    // per-XCD claim counters
#define F_CHECKIN   512              // rendezvous counter
#define F_SPILL     576              // surplus slot allocator

typedef __attribute__((ext_vector_type(8))) short short8;
typedef __attribute__((ext_vector_type(4))) float float4v;
typedef __attribute__((ext_vector_type(4))) unsigned int uint4v;

__device__ __forceinline__ float sigmoid_f(float x) {
    return 1.f / (1.f + __expf(-x));
}
__device__ __forceinline__ float tanh_f(float x) {
    float ax = fabsf(x);
    float e = __expf(2.f * ax);
    float t = 1.f - 2.f / (e + 1.f);
    return copysignf(t, x);
}
__device__ __forceinline__ short bf16bits(float f) {
    union { __hip_bfloat16 b; short s; } u;
    u.b = __float2bfloat16(f);
    return u.s;
}
__device__ __forceinline__ short8 load8f(const float* p) {   // fp32 -> bf16 frag
    float4v lo = *(const float4v*)p;
    float4v hi = *(const float4v*)(p + 4);
    short8 r;
    r[0] = bf16bits(lo[0]); r[1] = bf16bits(lo[1]);
    r[2] = bf16bits(lo[2]); r[3] = bf16bits(lo[3]);
    r[4] = bf16bits(hi[0]); r[5] = bf16bits(hi[1]);
    r[6] = bf16bits(hi[2]); r[7] = bf16bits(hi[3]);
    return r;
}
__device__ __forceinline__ short8 load8b(const __hip_bfloat16* p) {
    return *(const short8*)p;
}

// ---------------------------------------------------------------------------
// raw buffer ops. aux=17 (sc0|sc1): LLC-direct, cross-XCD coherent (export
// path). aux=1 (sc0): bypass L1, read own-XCD L2 — coherent with same-XCD
// writeback stores by construction (local path; no fences needed).
// ---------------------------------------------------------------------------
#if __has_builtin(__builtin_amdgcn_make_buffer_rsrc) && \
    __has_builtin(__builtin_amdgcn_raw_buffer_load_b128) && \
    __has_builtin(__builtin_amdgcn_raw_buffer_store_b128)
typedef __amdgpu_buffer_rsrc_t srd_t;
__device__ __forceinline__ srd_t make_srd(const void* p) {
    return __builtin_amdgcn_make_buffer_rsrc(const_cast<void*>(p), (short)0,
                                             0xFFFFFFFFu, 0x00020000);
}
__device__ __forceinline__ short8 bload16(srd_t srd, int voff, int soff) {
    union { uint4v u; short8 s; } c;
    c.u = __builtin_amdgcn_raw_buffer_load_b128(srd, voff, soff, 17);
    return c.s;
}
__device__ __forceinline__ short8 bload16_l2(srd_t srd, int voff, int soff) {
    union { uint4v u; short8 s; } c;
    c.u = __builtin_amdgcn_raw_buffer_load_b128(srd, voff, soff, 1);
    return c.s;
}
__device__ __forceinline__ void bstore16(short8 v, srd_t srd, int voff) {
    union { uint4v u; short8 s; } c; c.s = v;
    __builtin_amdgcn_raw_buffer_store_b128(c.u, srd, voff, 0, 17);
}
#else
typedef const char* srd_t;
__device__ __forceinline__ srd_t make_srd(const void* p) {
    return (const char*)p;
}
__device__ __forceinline__ short8 bload16(srd_t srd, int voff, int soff) {
    const char* base = srd + voff + soff;
    union { unsigned long long q[2]; short8 s; } u;
    u.q[0] = __hip_atomic_load((const unsigned long long*)base,
                               __ATOMIC_RELAXED, __HIP_MEMORY_SCOPE_AGENT);
    u.q[1] = __hip_atomic_load((const unsigned long long*)(base + 8),
                               __ATOMIC_RELAXED, __HIP_MEMORY_SCOPE_AGENT);
    return u.s;
}
__device__ __forceinline__ short8 bload16_l2(srd_t srd, int voff, int soff) {
    return bload16(srd, voff, soff);   // conservative
}
__device__ __forceinline__ void bstore16(short8 v, srd_t srd, int voff) {
    char* base = const_cast<char*>(srd) + voff;
    union { unsigned long long q[2]; short8 s; } u; u.s = v;
    __hip_atomic_store((unsigned long long*)base, u.q[0],
                       __ATOMIC_RELAXED, __HIP_MEMORY_SCOPE_AGENT);
    __hip_atomic_store((unsigned long long*)(base + 8), u.q[1],
                       __ATOMIC_RELAXED, __HIP_MEMORY_SCOPE_AGENT);
}
#endif

__host__ __device__ constexpr size_t hidx(int s, int l, int j, int m, int c) {
    return ((((size_t)s * NL + l) * 32 + j) * 256 + m) * 16 + c;
}

// ---------------------------------------------------------------------------
// init: h0 fp32 -> bf16 parity-1 slot of BOTH export (ws) and local (d_out
// scratch) h buffers; zero all flags.
// ---------------------------------------------------------------------------
__global__ void init_state_k(const float* __restrict__ h0,
                             __hip_bfloat16* __restrict__ hbuf,
                             __hip_bfloat16* __restrict__ hloc,
                             int* __restrict__ flags) {
    int i = blockIdx.x * 256 + threadIdx.x;   // grid covers NL*BH exactly
    int l = i / BH, r = i % BH;
    int m = r >> 9, col = r & 511;
    size_t o = hidx(1, l, col >> 4, m, col & 15);
    __hip_bfloat16 v = __float2bfloat16(h0[i]);
    hbuf[o] = v;
    hloc[o] = v;
    if (blockIdx.x == 0) {
        flags[threadIdx.x] = 0;
        flags[threadIdx.x + 256] = 0;
        flags[threadIdx.x + 512] = 0;
    }
}

// ---------------------------------------------------------------------------
// the per-block persistent LSTM body. FAST=1: h_prev via own-XCD L2 (plain
// writeback stores + sc0 loads; producer/consumer colocated by claim phase).
// FAST=0: h_prev via sc1 LLC-direct (round-2 exact). h_in always sc1.
// Numerics identical in both modes.
// ---------------------------------------------------------------------------
template<int FAST>
__device__ __forceinline__ void lstm_run(
    const int* __restrict__ x, const float* __restrict__ emb,
    const float* __restrict__ W_ih, const float* __restrict__ W_hh,
    const float* __restrict__ b_ih, const float* __restrict__ b_hh,
    const float* __restrict__ c0,
    __hip_bfloat16* __restrict__ hbuf,   // export buffer (ws)
    __hip_bfloat16* __restrict__ hloc,   // local buffer (d_out scratch)
    int* __restrict__ flags, int l, int j,
    short* __restrict__ lw, short8 (*__restrict__ xch)[32])
{
    const int tid = threadIdx.x;
    const int jbase = j << 4;
    const int wave = tid >> 6, lane = tid & 63;
    const int quad = lane >> 4, l16 = lane & 15;
    const int m16 = wave << 4;

    const float* Wg[2] = { W_ih + (size_t)l * G4H * HID,
                           W_hh + (size_t)l * G4H * HID };

    // ---- stage weight slice into LDS in fragment order ----
    for (int e = tid; e < 8192; e += 1024) {
        int row = e >> 6;
        int kc  = (e & 63) << 3;
        int gemm = row >> 6, r2 = row & 63, g = r2 >> 4, rl = r2 & 15;
        const float* src = Wg[gemm] + (size_t)(g * HID + jbase + rl) * HID + kc;
        short8 v = load8f(src);
        int kt = kc >> 5, q = (kc >> 3) & 3;
        int fragslot = ((gemm * 4 + g) * 16 + kt) * 64 + (q * 16 + rl);
        *(short8*)&lw[(size_t)fragslot * 8] = v;
    }

    // ---- per-lane persistent state ----
    const int jj = jbase + l16;
    float bias[4], c_r[4];
#pragma unroll
    for (int g = 0; g < 4; ++g)
        bias[g] = b_ih[l * G4H + g * HID + jj] + b_hh[l * G4H + g * HID + jj];
#pragma unroll
    for (int r = 0; r < 4; ++r)
        c_r[r] = c0[(size_t)l * BH + (size_t)(m16 + quad * 4 + r) * HID + jj];

    const short* lwb = lw + (size_t)lane * 8;
    const int shi = quad >> 1;                // slice parity from quad
    const int abyte = ((m16 + l16) * 16 + (quad & 1) * 8) * 2 + shi * 8192;
    const srd_t hsrd = make_srd(hbuf);
    const srd_t lsrd = make_srd(hloc);

    __syncthreads();

    for (int t = 0; t < SEQ; ++t) {
        // ---- dependency wait (tid0 polls, then barrier) ----
        if (tid == 0) {
            if (l > 0) {
                int need = 32 * (t + 1);
                while (__hip_atomic_load(&flags[F_DONE(l - 1)], __ATOMIC_RELAXED,
                                         __HIP_MEMORY_SCOPE_AGENT) < need)
                    __builtin_amdgcn_s_sleep(1);
            }
            if (t > 0) {
                int need = 32 * t;
                while (__hip_atomic_load(&flags[F_DONE(l)], __ATOMIC_RELAXED,
                                         __HIP_MEMORY_SCOPE_AGENT) < need)
                    __builtin_amdgcn_s_sleep(1);
            }
            if (l < NL - 1 && t >= 2) {        // WAR throttle, reuse dist 2
                int need = 32 * (t - 1);
                while (__hip_atomic_load(&flags[F_DONE(l + 1)], __ATOMIC_RELAXED,
                                         __HIP_MEMORY_SCOPE_AGENT) < need)
                    __builtin_amdgcn_s_sleep(1);
            }
        }
        __syncthreads();

        const int p = t & 1, pm1 = p ^ 1;
        const int vpr = pm1 * SLOTB + l * LAYB + abyte;

        float4v acc[4];
#pragma unroll
        for (int g = 0; g < 4; ++g) acc[g] = (float4v){0.f, 0.f, 0.f, 0.f};

        if (l == 0) {
            int tok = x[t * BATCH + m16 + l16];
            const float* ar = emb + (size_t)tok * HID;
            short8 ah[4];
#pragma unroll
            for (int d = 0; d < 4; ++d)
                ah[d] = FAST ? bload16_l2(lsrd, vpr, d * 16384)
                             : bload16(hsrd, vpr, d * 16384);
#pragma unroll
            for (int kt = 0; kt < 16; ++kt) {
                short8 a_in = load8f(ar + kt * 32 + quad * 8);
                short8 a_h = ah[kt & 3];
                if (kt + 4 < 16)
                    ah[kt & 3] = FAST ? bload16_l2(lsrd, vpr, (kt + 4) * 16384)
                                      : bload16(hsrd, vpr, (kt + 4) * 16384);
#pragma unroll
                for (int g = 0; g < 4; ++g) {
                    short8 b0 = *(const short8*)(lwb + (size_t)(g * 16 + kt) * 512);
                    short8 b1 = *(const short8*)(lwb + (size_t)((4 + g) * 16 + kt) * 512);
                    acc[g] = __builtin_amdgcn_mfma_f32_16x16x32_bf16(a_in, b0, acc[g], 0, 0, 0);
                    acc[g] = __builtin_amdgcn_mfma_f32_16x16x32_bf16(a_h,  b1, acc[g], 0, 0, 0);
                }
            }
        } else {
            const int vin = p * SLOTB + (l - 1) * LAYB + abyte;
            short8 ai[4], ah[4];
#pragma unroll
            for (int d = 0; d < 4; ++d) {
                ai[d] = bload16(hsrd, vin, d * 16384);
                ah[d] = FAST ? bload16_l2(lsrd, vpr, d * 16384)
                             : bload16(hsrd, vpr, d * 16384);
            }
#pragma unroll
            for (int kt = 0; kt < 16; ++kt) {
                short8 a_in = ai[kt & 3];
                short8 a_h  = ah[kt & 3];
                if (kt + 4 < 16) {
                    ai[kt & 3] = bload16(hsrd, vin, (kt + 4) * 16384);
                    ah[kt & 3] = FAST ? bload16_l2(lsrd, vpr, (kt + 4) * 16384)
                                      : bload16(hsrd, vpr, (kt + 4) * 16384);
                }
#pragma unroll
                for (int g = 0; g < 4; ++g) {
                    short8 b0 = *(const short8*)(lwb + (size_t)(g * 16 + kt) * 512);
                    short8 b1 = *(const short8*)(lwb + (size_t)((4 + g) * 16 + kt) * 512);
                    acc[g] = __builtin_amdgcn_mfma_f32_16x16x32_bf16(a_in, b0, acc[g], 0, 0, 0);
                    acc[g] = __builtin_amdgcn_mfma_f32_16x16x32_bf16(a_h,  b1, acc[g], 0, 0, 0);
                }
            }
        }

        // ---- epilogue: register c; per-wave LDS transpose, then 16B
        //      stores: export (sc1, cross-XCD) + local (writeback, own L2) ----
        short* xp = (short*)&xch[wave];
#pragma unroll
        for (int r = 0; r < 4; ++r) {
            float iv = sigmoid_f(acc[0][r] + bias[0]);
            float fv = sigmoid_f(acc[1][r] + bias[1]);
            float gv = tanh_f(acc[2][r] + bias[2]);
            float ov = sigmoid_f(acc[3][r] + bias[3]);
            c_r[r] = fv * c_r[r] + iv * gv;
            xp[(quad * 4 + r) * 16 + l16] = bf16bits(ov * tanh_f(c_r[r]));
        }
        __builtin_amdgcn_wave_barrier();      // order LDS write -> read in-wave
        if (lane < 32) {
            short8 v = *(const short8*)&xp[lane * 8];
            int vout = p * SLOTB + l * LAYB + j * 8192 + m16 * 32 + lane * 16;
            bstore16(v, hsrd, vout);
            if (FAST)
                *(short8*)((char*)hloc + vout) = v;
        }

        __syncthreads();   // all waves' stores drained (vmcnt) before flag
        if (tid == 0)
            __hip_atomic_fetch_add(&flags[F_DONE(l)], 1, __ATOMIC_RELEASE,
                                   __HIP_MEMORY_SCOPE_AGENT);
    }
}

// ---------------------------------------------------------------------------
// persistent kernel wrapper: claim phase (physical-XCD discovery + slot
// assignment + rendezvous) then templated body. 256 blocks, 1/CU; inactive
// blocks exit after the rendezvous.
// ---------------------------------------------------------------------------
__global__ __launch_bounds__(1024) void lstm_persist_k(
    const int* __restrict__ x,
    const float* __restrict__ emb,
    const float* __restrict__ W_ih,
    const float* __restrict__ W_hh,
    const float* __restrict__ b_ih,
    const float* __restrict__ b_hh,
    const float* __restrict__ c0,
    __hip_bfloat16* __restrict__ hbuf,
    __hip_bfloat16* __restrict__ hloc,
    int* __restrict__ flags)
{
    __shared__ short lw[65536];               // 128 KB weight slice
    __shared__ short8 xch[16][32];            // 8 KB per-wave store transpose
    __shared__ int info[3];

    const int tid = threadIdx.x;
    if (tid == 0) {
        unsigned xcc;
#if __has_builtin(__builtin_amdgcn_s_getreg)
        // hwreg(HW_REG_XCC_ID=20, offset=0, size=32): 20 | (31<<11) = 63508
        xcc = (unsigned)__builtin_amdgcn_s_getreg(63508) & 7u;
#else
        xcc = (unsigned)(blockIdx.x & 7);
#endif
        int pos = __hip_atomic_fetch_add(&flags[F_CLAIM(xcc)], 1,
                                         __ATOMIC_RELAXED, __HIP_MEMORY_SCOPE_AGENT);
        __hip_atomic_fetch_add(&flags[F_CHECKIN], 1,
                               __ATOMIC_RELEASE, __HIP_MEMORY_SCOPE_AGENT);
        while (__hip_atomic_load(&flags[F_CHECKIN], __ATOMIC_RELAXED,
                                 __HIP_MEMORY_SCOPE_AGENT) < NBLK_LAUNCH)
            __builtin_amdgcn_s_sleep(8);
        __builtin_amdgcn_fence(__ATOMIC_ACQUIRE, "agent");

        int cl[5]; int fast = 1;
        for (int i = 0; i < 5; ++i) {
            int c = __hip_atomic_load(&flags[F_CLAIM(i)], __ATOMIC_RELAXED,
                                      __HIP_MEMORY_SCOPE_AGENT);
            cl[i] = c > 32 ? 32 : c;
            if (cl[i] < 32) fast = 0;
        }
        int layer = -1, jslice = 0;
        if (xcc < 5 && pos < 32) {
            layer = (int)xcc; jslice = pos;      // colocated claim
        } else {
            // surplus: deterministically fill unclaimed (layer, j) slots
            int k = __hip_atomic_fetch_add(&flags[F_SPILL], 1,
                                           __ATOMIC_RELAXED, __HIP_MEMORY_SCOPE_AGENT);
            int cum = 0;
            for (int i = 0; i < 5; ++i) {
                int d = 32 - cl[i];
                if (k < cum + d) { layer = i; jslice = cl[i] + (k - cum); break; }
                cum += d;
            }
        }
        info[0] = layer; info[1] = jslice; info[2] = fast;
    }
    __syncthreads();
    const int l = info[0], j = info[1], fast = info[2];
    if (l < 0) return;                        // idle block (uniform per block)

    if (fast)
        lstm_run<1>(x, emb, W_ih, W_hh, b_ih, b_hh, c0, hbuf, hloc, flags,
                    l, j, lw, xch);
    else
        lstm_run<0>(x, emb, W_ih, W_hh, b_ih, b_hh, c0, hbuf, hloc, flags,
                    l, j, lw, xch);
}

// ---------------------------------------------------------------------------
// output projection: out(256 x 32000) = h_final @ W_out^T + b_out
// ---------------------------------------------------------------------------
__global__ __launch_bounds__(512) void out_gemm_k(
    const __hip_bfloat16* __restrict__ hfin,
    const float* __restrict__ W_out,
    const float* __restrict__ b_out,
    float* __restrict__ out)
{
    const int nb = blockIdx.x;
    const int tid = threadIdx.x;
    const int wave = tid >> 6, lane = tid & 63;
    const int quad = lane >> 4, l16 = lane & 15;
    const int nt = wave & 3, mh = wave >> 2;

    const int shi = quad >> 1;
    const size_t coff = (size_t)(quad & 1) * 8;

    const int ncol = nb * 64 + nt * 16 + l16;
    const float* brow = W_out + (size_t)ncol * HID;

    float4v acc[8];
#pragma unroll
    for (int mt = 0; mt < 8; ++mt) acc[mt] = (float4v){0.f, 0.f, 0.f, 0.f};

#pragma unroll 2
    for (int kt = 0; kt < 16; ++kt) {
        short8 b = load8f(brow + kt * 32 + quad * 8);
        const __hip_bfloat16* abase =
            hfin + (size_t)(2 * kt + shi) * 4096 + coff;
#pragma unroll
        for (int mt = 0; mt < 8; ++mt) {
            short8 a = load8b(abase + (size_t)(mh * 128 + mt * 16 + l16) * 16);
            acc[mt] = __builtin_amdgcn_mfma_f32_16x16x32_bf16(a, b, acc[mt], 0, 0, 0);
        }
    }

    float bo = b_out[ncol];
#pragma unroll
    for (int mt = 0; mt < 8; ++mt) {
#pragma unroll
        for (int r = 0; r < 4; ++r) {
            int m = mh * 128 + mt * 16 + quad * 4 + r;
            out[(size_t)m * VOCAB + ncol] = acc[mt][r] + bo;
        }
    }
}

extern "C" void kernel_launch(void* const* d_in, const int* in_sizes, int n_in,
                              void* d_out, int out_size, void* d_ws, size_t ws_size,
                              hipStream_t stream) {
    const int* x        = (const int*)d_in[0];
    const float* h0     = (const float*)d_in[1];
    const float* c0     = (const float*)d_in[2];
    const float* emb    = (const float*)d_in[3];
    const float* W_ih   = (const float*)d_in[4];
    const float* W_hh   = (const float*)d_in[5];
    const float* b_ih   = (const float*)d_in[6];
    const float* b_hh   = (const float*)d_in[7];
    const float* W_out  = (const float*)d_in[8];
    const float* b_out  = (const float*)d_in[9];
    float* out          = (float*)d_out;

    // ws: export h buffer (2 parity slots) + flags page (same as round 2).
    // local h buffer (2 parity slots) lives in d_out scratch (32.77 MB,
    // fully overwritten by out_gemm afterwards).
    __hip_bfloat16* hbuf = (__hip_bfloat16*)d_ws;
    int* flags = (int*)((char*)d_ws + (size_t)2 * SLOTB);
    __hip_bfloat16* hloc = (__hip_bfloat16*)d_out;

    init_state_k<<<(NL * BH) / 256, 256, 0, stream>>>(h0, hbuf, hloc, flags);

    lstm_persist_k<<<NBLK_LAUNCH, 1024, 0, stream>>>(x, emb, W_ih, W_hh, b_ih,
                                                     b_hh, c0, hbuf, hloc, flags);

    out_gemm_k<<<VOCAB / 64, 512, 0, stream>>>(
        hbuf + hidx(1, NL - 1, 0, 0, 0), W_out, b_out, out);
}